// Round 12
// baseline (107.159 us; speedup 1.0000x reference)
//
#include <hip/hip_runtime.h>
#include <hip/hip_bf16.h>

#define B_    32
#define C_    128
#define L_    4096
#define P_    100
#define NPT   7            // p-tiles of 16 (P padded to 112)
#define Q_    20
#define NBIN  21
#define HSTR  37           // R7: padded hist row stride: collision only at Δnn=±13
#define NCH   (NPT * 4)    // 28 A-frag chunks; chunk = pt*4 + ks
#define CHS   512          // shorts per chunk = 64 lanes * 8 bf16 (1 KB)
#define TPB   1024         // 16-wave blocks (R4/R8 verified shape)
#define LSPAN 512          // l-columns per block

typedef short          bf16x8 __attribute__((ext_vector_type(8)));
typedef float          f32x4  __attribute__((ext_vector_type(4)));
typedef float          f32x2  __attribute__((ext_vector_type(2)));
typedef unsigned short u16x8  __attribute__((ext_vector_type(8)));

__device__ inline unsigned short f2bf(float f) {
    __hip_bfloat16 h = __float2bfloat16(f);   // RNE
    unsigned short u; __builtin_memcpy(&u, &h, 2);
    return u;
}

// ---- prep: W (fp32 [P][C]) -> bf16 fragment lane order in d_ws ----
// Wf[chunk][lane][j], chunk=pt*4+ks: value = W[pt*16 + (lane&15)][ks*32 + (lane>>4)*8 + j]
// (rows p>=100 zeroed). Main kernel copies with plain dwordx4 -> conflict-free
// ds_read_b128 fragments.
__global__ void prep_w_kernel(const float* __restrict__ W, unsigned short* __restrict__ Wf) {
    const int t = blockIdx.x * 256 + threadIdx.x;     // 0 .. NCH*64-1
    if (t >= NCH * 64) return;
    const int chunk = t >> 6, lane = t & 63;
    const int pt = chunk >> 2, ks = chunk & 3;
    const int p  = pt * 16 + (lane & 15);
    const int c0 = ks * 32 + (lane >> 4) * 8;
    u16x8 v;
#pragma unroll
    for (int j = 0; j < 8; ++j)
        v[j] = (p < P_) ? f2bf(W[p * C_ + c0 + j]) : (unsigned short)0;
    *(u16x8*)(Wf + (size_t)t * 8) = v;                // 16B coalesced store
}

// ---- main: block = (b, 512-l span), 16 waves; wave owns 32 l ----
// D[p][l] = sum_c W[p][c] * X[b][c][l] via mfma_f32_16x16x32_bf16.
//
// R10 change (single variable on the R8-verified 102.55 kernel): NON-TEMPORAL
// X LOADS. Theory: the harness's per-iteration poison fills leave 256 MiB of
// DIRTY lines in L3; our 64 MiB X stream evicts ~64 MiB of them, so HBM serves
// read + write-back concurrently -> observed ~2.6-3.6 TB/s (~65% eff) in every
// variant, and radon FETCH 79-83 MB vs 64 ideal. X has ZERO reuse (each line
// read once by one wave) -> __builtin_nontemporal_load (nt-flagged
// global_load_dwordx2) skips cache allocation, no dirty evictions during the
// stream. Identical values loaded => identical absmax.
//
// R9 post-mortem (evidence): float4 + 8 waves/CU REGRESSED (+2.2 us) despite
// halved VMEM instr count -> stream is MLP/occupancy-bound, not issue-bound.
// R8's shape (16 waves/CU, all 32 loads issued upfront, 512 outstanding/CU)
// is the MLP maximum; kept exactly.
//
// R8 (kept): full-line dwordx2 via even/odd lt-interleave (tile0=l0+2i,
// tile1=l0+2i+1); histogram is l-independent so Phases C/D unchanged.
// R7 (kept): hist stride 37 + two-step prefix epilogue.
// R2 (kept): swapped MFMA operands -> D row=l-idx(quad*4+r), col=p(nn):
//   A'[m][k]=X[ks*32+k][l0+2m+lt], B'[k][n]=W[pt*16+n][ks*32+k]
//   => D'[m][n] = a[b, p=pt*16+n, l=l0+2*(quad*4+r)+lt]  (m89-verified C/D map)
//
// PHASE ORDER (kept): the ONLY pre-epilogue barrier happens BEFORE any X load;
// afterwards each wave streams loads -> cvt -> ds_read -> MFMA -> bucket with
// no barrier. Histogram: 21 uniform bins, prefix epilogue, exact fp32
// atomicAdd (counts <= 4096, multiples of 2^-12 -> exact).
__global__ __launch_bounds__(TPB, 4)
void radon_mfma11_kernel(const float* __restrict__ X, const unsigned short* __restrict__ Wf,
                         const float* __restrict__ minv, const float* __restrict__ maxv,
                         float* __restrict__ out) {
    __shared__ unsigned short Wlds[NCH * CHS];   // 28.0 KB
    __shared__ int   hist[P_ * HSTR];            // 14.8 KB (stride-37 rows)
    __shared__ float mn_s[P_], invd_s[P_];       // 0.8 KB

    const int tid  = threadIdx.x;
    const int b    = blockIdx.y;
    const int lblk = blockIdx.x;       // 0..7
    const int wave = tid >> 6;         // 0..15
    const int lane = tid & 63;
    const int quad = lane >> 4;
    const int nn   = lane & 15;

    // ---- Phase A: Wf -> LDS (plain dwordx4 copy), thresholds, hist zero, barrier.
    {
        const int4* src = (const int4*)Wf;
        int4* dst = (int4*)Wlds;
        for (int k = tid; k < NCH * 64; k += TPB)    // 1792 int4, L2-resident
            dst[k] = src[k];
    }
    for (int i = tid; i < P_; i += TPB) {
        const float mn = minv[i];
        mn_s[i]   = mn;
        invd_s[i] = (float)NBIN / (maxv[i] - mn);
    }
    for (int i = tid; i < P_ * HSTR; i += TPB) hist[i] = 0;
    __syncthreads();   // the ONLY barrier before the bucket epilogue

    // ---- Phase B: full-line nontemporal float2 X loads + packed cvt.
    // lane nn covers columns l0 + 2nn (.x -> tile0) and l0 + 2nn + 1 (.y -> tile1)
    const int l0 = lblk * LSPAN + wave * 32;
    const float* Xb = X + (size_t)b * C_ * L_ + l0 + 2 * nn;
    f32x2 xv[4][8];
#pragma unroll
    for (int ks = 0; ks < 4; ++ks)
#pragma unroll
        for (int j = 0; j < 8; ++j)
            xv[ks][j] = __builtin_nontemporal_load(
                (const f32x2*)(Xb + (size_t)(ks * 32 + quad * 8 + j) * L_));

    bf16x8 bfrag[2][4];
#pragma unroll
    for (int ks = 0; ks < 4; ++ks) {
        unsigned int u0[4], u1[4];
#pragma unroll
        for (int jp = 0; jp < 4; ++jp) {
            __hip_bfloat162 h2;
            h2 = __float22bfloat162_rn(make_float2(xv[ks][2 * jp][0], xv[ks][2 * jp + 1][0]));
            __builtin_memcpy(&u0[jp], &h2, 4);
            h2 = __float22bfloat162_rn(make_float2(xv[ks][2 * jp][1], xv[ks][2 * jp + 1][1]));
            __builtin_memcpy(&u1[jp], &h2, 4);
        }
        __builtin_memcpy(&bfrag[0][ks], u0, 16);
        __builtin_memcpy(&bfrag[1][ks], u1, 16);
    }

    // ---- Phase C: 7 p-tiles, no barrier: ds_read W-frags + 8 MFMAs + bucket
    // p = pt*16 + nn is PER-THREAD CONSTANT within a pt iteration.
    for (int pt = 0; pt < NPT; ++pt) {
        bf16x8 afrag[4];
#pragma unroll
        for (int ks = 0; ks < 4; ++ks)
            afrag[ks] = *(const bf16x8*)(&Wlds[((pt * 4 + ks) * 64 + lane) * 8]);

        f32x4 acc0 = {0.f, 0.f, 0.f, 0.f};
        f32x4 acc1 = {0.f, 0.f, 0.f, 0.f};
#pragma unroll
        for (int ks = 0; ks < 4; ++ks) {
            // swapped operands: D row = l-index (quad*4+r), col = p (nn)
            acc0 = __builtin_amdgcn_mfma_f32_16x16x32_bf16(bfrag[0][ks], afrag[ks], acc0, 0, 0, 0);
            acc1 = __builtin_amdgcn_mfma_f32_16x16x32_bf16(bfrag[1][ks], afrag[ks], acc1, 0, 0, 0);
        }

        const int p = pt * 16 + nn;
        if (p < P_) {
            const float mn = mn_s[p], invd = invd_s[p];
            int* __restrict__ hrow = &hist[p * HSTR];
#pragma unroll
            for (int r = 0; r < 4; ++r) {
                {
                    const float t = (acc0[r] - mn) * invd;
                    int k = 0;
                    if (t > 0.f) { const int ki = (int)t; k = (ki > 20) ? 20 : ki; }
                    atomicAdd(&hrow[k], 1);
                }
                {
                    const float t = (acc1[r] - mn) * invd;
                    int k = 0;
                    if (t > 0.f) { const int ki = (int)t; k = (ki > 20) ? 20 : ki; }
                    atomicAdd(&hrow[k], 1);
                }
            }
        }
    }
    __syncthreads();

    // ---- Phase D step 1: in-place prefix per p (one thread per row)
    if (tid < P_) {
        int* row = &hist[tid * HSTR];
        int run = 0;
#pragma unroll
        for (int k = 0; k < NBIN; ++k) { run += row[k]; row[k] = run; }
    }
    __syncthreads();

    // ---- Phase D step 2: one LDS read per output -> exact fp32 atomic accumulation
    for (int i = tid; i < P_ * Q_; i += TPB) {
        const int p  = i / Q_;
        const int qi = i - p * Q_;
        const int s  = hist[p * HSTR + qi];   // prefix over bins 0..qi
        atomicAdd(&out[((size_t)b * P_ + p) * Q_ + qi], (float)s * (1.0f / (float)L_));
    }
}

extern "C" void kernel_launch(void* const* d_in, const int* in_sizes, int n_in,
                              void* d_out, int out_size, void* d_ws, size_t ws_size,
                              hipStream_t stream) {
    const float* X  = (const float*)d_in[0];
    const float* W  = (const float*)d_in[1];
    const float* mn = (const float*)d_in[2];
    const float* mx = (const float*)d_in[3];
    float* out = (float*)d_out;
    unsigned short* Wf = (unsigned short*)d_ws;   // needs NCH*64*16 = 28672 bytes

    hipMemsetAsync(out, 0, (size_t)out_size * sizeof(float), stream);
    prep_w_kernel<<<NCH * 64 / 256, 256, 0, stream>>>(W, Wf);

    dim3 grid(L_ / LSPAN, B_);
    radon_mfma11_kernel<<<grid, dim3(TPB), 0, stream>>>(X, Wf, mn, mx, out);
}

// Round 13
// 102.668 us; speedup vs baseline: 1.0437x; 1.0437x over previous
//
#include <hip/hip_runtime.h>
#include <hip/hip_bf16.h>

#define B_    32
#define C_    128
#define L_    4096
#define P_    100
#define NPT   7            // p-tiles of 16 (P padded to 112)
#define Q_    20
#define NBIN  21
#define HSTR  37           // R7: padded hist row stride: collision only at Δnn=±13
#define NCH   (NPT * 4)    // 28 A-frag chunks; chunk = pt*4 + ks
#define CHS   512          // shorts per chunk = 64 lanes * 8 bf16 (1 KB)
#define TPB   1024         // 16-wave blocks (R4/R8 verified shape)
#define LSPAN 512          // l-columns per block

typedef short          bf16x8 __attribute__((ext_vector_type(8)));
typedef float          f32x4  __attribute__((ext_vector_type(4)));
typedef unsigned short u16x8  __attribute__((ext_vector_type(8)));

__device__ inline unsigned short f2bf(float f) {
    __hip_bfloat16 h = __float2bfloat16(f);   // RNE
    unsigned short u; __builtin_memcpy(&u, &h, 2);
    return u;
}

// ---- prep: W (fp32 [P][C]) -> bf16 fragment lane order in d_ws ----
// Wf[chunk][lane][j], chunk=pt*4+ks: value = W[pt*16 + (lane&15)][ks*32 + (lane>>4)*8 + j]
// (rows p>=100 zeroed). Main kernel copies with plain dwordx4 -> conflict-free
// ds_read_b128 fragments.
__global__ void prep_w_kernel(const float* __restrict__ W, unsigned short* __restrict__ Wf) {
    const int t = blockIdx.x * 256 + threadIdx.x;     // 0 .. NCH*64-1
    if (t >= NCH * 64) return;
    const int chunk = t >> 6, lane = t & 63;
    const int pt = chunk >> 2, ks = chunk & 3;
    const int p  = pt * 16 + (lane & 15);
    const int c0 = ks * 32 + (lane >> 4) * 8;
    u16x8 v;
#pragma unroll
    for (int j = 0; j < 8; ++j)
        v[j] = (p < P_) ? f2bf(W[p * C_ + c0 + j]) : (unsigned short)0;
    *(u16x8*)(Wf + (size_t)t * 8) = v;                // 16B coalesced store
}

// ---- main: block = (b, 512-l span), 16 waves; wave owns 32 l ----
// D[p][l] = sum_c W[p][c] * X[b][c][l] via mfma_f32_16x16x32_bf16.
//
// R11: REVERT TO THE VERIFIED BEST (R8, 102.55 us). Final lever ledger:
//  - R8 full-line dwordx2 via even/odd lt-interleave: WIN (+1.5 us), kept.
//  - R4 16-wave block merge: WIN (+4.3 us), kept.
//  - R7 hist stride 37 + two-step prefix epilogue: WIN (+0.8 us), kept.
//  - R6 ks-outer prefetch interleave: NEUTRAL (tail already hides under
//    stream via wave TLP).
//  - R9 float4 + 8 waves/CU: REGRESS (+2.2) — stream is MLP-bound; 16 waves
//    with all 32 loads issued upfront is the MLP optimum.
//  - R10 nontemporal loads: REGRESS (+4.6) — nt forfeits L2 merging; the
//    "overfetch" evidence behind it came from SPILLED variants' scratch
//    read-back (clean kernels' FETCH never measured).
//  - R3/R5 lt-split pipelines: SPILL (VGPR=64 + 40-54 MB scratch traffic)
//    whenever a raw 32-fp32 tile stays live across a compute region.
// Measured window = ~83.4 us unconditional harness workspace-poison fills
// + ~0.7 prep/memset + ~18.5 radon (vs ~11 us pure-stream floor).
//
// R8: lane nn loads float2 at l0+2nn: one instruction per (ks,j) covers
// 4 rows x 128 B FULL cache lines — 32 VMEM instr/thread. tile0=.x (even
// cols), tile1=.y (odd cols); histogram is l-independent so Phases C/D
// identical to the R7 form.
// R2: swapped MFMA operands -> D row=l-idx(quad*4+r), col=p(nn):
//   A'[m][k]=X[ks*32+k][l0+2m+lt], B'[k][n]=W[pt*16+n][ks*32+k]
//   => D'[m][n] = a[b, p=pt*16+n, l=l0+2*(quad*4+r)+lt]  (m89-verified C/D map)
//
// PHASE ORDER: the ONLY pre-epilogue barrier happens BEFORE any X load
// (__syncthreads drains vmcnt(0) — a barrier after loads would lockstep all
// waves); afterwards each wave streams loads -> cvt -> ds_read -> MFMA ->
// bucket with no barrier. Histogram: 21 uniform bins, prefix epilogue,
// exact fp32 atomicAdd (counts <= 4096, multiples of 2^-12 -> exact).
__global__ __launch_bounds__(TPB, 4)
void radon_mfma9_kernel(const float* __restrict__ X, const unsigned short* __restrict__ Wf,
                        const float* __restrict__ minv, const float* __restrict__ maxv,
                        float* __restrict__ out) {
    __shared__ unsigned short Wlds[NCH * CHS];   // 28.0 KB
    __shared__ int   hist[P_ * HSTR];            // 14.8 KB (stride-37 rows)
    __shared__ float mn_s[P_], invd_s[P_];       // 0.8 KB

    const int tid  = threadIdx.x;
    const int b    = blockIdx.y;
    const int lblk = blockIdx.x;       // 0..7
    const int wave = tid >> 6;         // 0..15
    const int lane = tid & 63;
    const int quad = lane >> 4;
    const int nn   = lane & 15;

    // ---- Phase A: Wf -> LDS (plain dwordx4 copy), thresholds, hist zero, barrier.
    {
        const int4* src = (const int4*)Wf;
        int4* dst = (int4*)Wlds;
        for (int k = tid; k < NCH * 64; k += TPB)    // 1792 int4, L2-resident
            dst[k] = src[k];
    }
    for (int i = tid; i < P_; i += TPB) {
        const float mn = minv[i];
        mn_s[i]   = mn;
        invd_s[i] = (float)NBIN / (maxv[i] - mn);
    }
    for (int i = tid; i < P_ * HSTR; i += TPB) hist[i] = 0;
    __syncthreads();   // the ONLY barrier before the bucket epilogue

    // ---- Phase B: full-line float2 X loads + packed cvt.
    // lane nn covers columns l0 + 2nn (.x -> tile0) and l0 + 2nn + 1 (.y -> tile1)
    const int l0 = lblk * LSPAN + wave * 32;
    const float* Xb = X + (size_t)b * C_ * L_ + l0 + 2 * nn;
    float2 xv[4][8];
#pragma unroll
    for (int ks = 0; ks < 4; ++ks)
#pragma unroll
        for (int j = 0; j < 8; ++j)
            xv[ks][j] = *(const float2*)(Xb + (size_t)(ks * 32 + quad * 8 + j) * L_);

    bf16x8 bfrag[2][4];
#pragma unroll
    for (int ks = 0; ks < 4; ++ks) {
        unsigned int u0[4], u1[4];
#pragma unroll
        for (int jp = 0; jp < 4; ++jp) {
            __hip_bfloat162 h2;
            h2 = __float22bfloat162_rn(make_float2(xv[ks][2 * jp].x, xv[ks][2 * jp + 1].x));
            __builtin_memcpy(&u0[jp], &h2, 4);
            h2 = __float22bfloat162_rn(make_float2(xv[ks][2 * jp].y, xv[ks][2 * jp + 1].y));
            __builtin_memcpy(&u1[jp], &h2, 4);
        }
        __builtin_memcpy(&bfrag[0][ks], u0, 16);
        __builtin_memcpy(&bfrag[1][ks], u1, 16);
    }

    // ---- Phase C: 7 p-tiles, no barrier: ds_read W-frags + 8 MFMAs + bucket
    // p = pt*16 + nn is PER-THREAD CONSTANT within a pt iteration.
    for (int pt = 0; pt < NPT; ++pt) {
        bf16x8 afrag[4];
#pragma unroll
        for (int ks = 0; ks < 4; ++ks)
            afrag[ks] = *(const bf16x8*)(&Wlds[((pt * 4 + ks) * 64 + lane) * 8]);

        f32x4 acc0 = {0.f, 0.f, 0.f, 0.f};
        f32x4 acc1 = {0.f, 0.f, 0.f, 0.f};
#pragma unroll
        for (int ks = 0; ks < 4; ++ks) {
            // swapped operands: D row = l-index (quad*4+r), col = p (nn)
            acc0 = __builtin_amdgcn_mfma_f32_16x16x32_bf16(bfrag[0][ks], afrag[ks], acc0, 0, 0, 0);
            acc1 = __builtin_amdgcn_mfma_f32_16x16x32_bf16(bfrag[1][ks], afrag[ks], acc1, 0, 0, 0);
        }

        const int p = pt * 16 + nn;
        if (p < P_) {
            const float mn = mn_s[p], invd = invd_s[p];
            int* __restrict__ hrow = &hist[p * HSTR];
#pragma unroll
            for (int r = 0; r < 4; ++r) {
                {
                    const float t = (acc0[r] - mn) * invd;
                    int k = 0;
                    if (t > 0.f) { const int ki = (int)t; k = (ki > 20) ? 20 : ki; }
                    atomicAdd(&hrow[k], 1);
                }
                {
                    const float t = (acc1[r] - mn) * invd;
                    int k = 0;
                    if (t > 0.f) { const int ki = (int)t; k = (ki > 20) ? 20 : ki; }
                    atomicAdd(&hrow[k], 1);
                }
            }
        }
    }
    __syncthreads();

    // ---- Phase D step 1: in-place prefix per p (one thread per row)
    if (tid < P_) {
        int* row = &hist[tid * HSTR];
        int run = 0;
#pragma unroll
        for (int k = 0; k < NBIN; ++k) { run += row[k]; row[k] = run; }
    }
    __syncthreads();

    // ---- Phase D step 2: one LDS read per output -> exact fp32 atomic accumulation
    for (int i = tid; i < P_ * Q_; i += TPB) {
        const int p  = i / Q_;
        const int qi = i - p * Q_;
        const int s  = hist[p * HSTR + qi];   // prefix over bins 0..qi
        atomicAdd(&out[((size_t)b * P_ + p) * Q_ + qi], (float)s * (1.0f / (float)L_));
    }
}

extern "C" void kernel_launch(void* const* d_in, const int* in_sizes, int n_in,
                              void* d_out, int out_size, void* d_ws, size_t ws_size,
                              hipStream_t stream) {
    const float* X  = (const float*)d_in[0];
    const float* W  = (const float*)d_in[1];
    const float* mn = (const float*)d_in[2];
    const float* mx = (const float*)d_in[3];
    float* out = (float*)d_out;
    unsigned short* Wf = (unsigned short*)d_ws;   // needs NCH*64*16 = 28672 bytes

    hipMemsetAsync(out, 0, (size_t)out_size * sizeof(float), stream);
    prep_w_kernel<<<NCH * 64 / 256, 256, 0, stream>>>(W, Wf);

    dim3 grid(L_ / LSPAN, B_);
    radon_mfma9_kernel<<<grid, dim3(TPB), 0, stream>>>(X, Wf, mn, mx, out);
}